// Round 1
// baseline (121.924 us; speedup 1.0000x reference)
//
#include <hip/hip_runtime.h>
#include <hip/hip_bf16.h>

#define BATCH 32
#define KP1   8193      // K+1
#define FEAT  128
#define SDIM  2048
#define KT    64        // k tiles per batch row
#define KPB   129       // ceil(8193/64)
#define NBLK_GATHER (KT * BATCH)   // 2048
#define NBLK_LOSS   512
#define TOT_OUT (BATCH * KP1)      // 262176

__device__ __forceinline__ float wave_reduce(float v) {
    #pragma unroll
    for (int off = 32; off > 0; off >>= 1) v += __shfl_xor(v, off);
    return v;
}

// ---------------- kernel 1: embed (linear + L2 norm) ----------------
__global__ void embed_kernel(const float* __restrict__ x_s, const float* __restrict__ x_t,
                             const float* __restrict__ W_s, const float* __restrict__ b_s,
                             const float* __restrict__ W_t, const float* __restrict__ b_t,
                             float* __restrict__ f_out /* f_s[32][128] then f_t[32][128] */) {
    __shared__ float xsh[SDIM];
    __shared__ float ysh[FEAT];
    __shared__ float red[4];
    int bid = blockIdx.x;          // 0..63
    int m   = bid >> 5;            // 0 = student, 1 = teacher
    int b   = bid & 31;
    const float* x    = (m ? x_t : x_s) + (size_t)b * SDIM;
    const float* W    = m ? W_t : W_s;
    const float* bias = m ? b_t : b_s;
    float* f = f_out + (size_t)m * BATCH * FEAT + (size_t)b * FEAT;

    int tid = threadIdx.x;
    for (int i = tid; i < SDIM; i += 256) xsh[i] = x[i];
    __syncthreads();

    int wave = tid >> 6, lane = tid & 63;
    for (int d = wave; d < FEAT; d += 4) {
        const float* Wr = W + (size_t)d * SDIM;
        float acc = 0.f;
        #pragma unroll 8
        for (int i = lane; i < SDIM; i += 64) acc += xsh[i] * Wr[i];
        acc = wave_reduce(acc);
        if (lane == 0) ysh[d] = acc + bias[d];
    }
    __syncthreads();

    float v = 0.f;
    if (tid < FEAT) { float y = ysh[tid]; v = y * y; }
    v = wave_reduce(v);
    if (lane == 0) red[wave] = v;
    __syncthreads();
    float sumsq = red[0] + red[1];
    float inv = 1.0f / sqrtf(sumsq);
    if (tid < FEAT) f[tid] = ysh[tid] * inv;
}

// ---------------- kernel 2: gather + dot + exp + partial sums ----------------
__global__ void gather_kernel(const float* __restrict__ mem_v1, const float* __restrict__ mem_v2,
                              const float* __restrict__ f,   // f_s then f_t
                              const int* __restrict__ idx, const int* __restrict__ cidx,
                              float* __restrict__ out_v1, float* __restrict__ out_v2,
                              float* __restrict__ partials /* [NBLK_GATHER][2] */) {
    const float INVT = 14.285714285714286f;  // 1/0.07
    int tile = blockIdx.x;    // 0..63
    int b    = blockIdx.y;    // 0..31
    int wave = threadIdx.x >> 6, lane = threadIdx.x & 63;

    const float2 fs2 = ((const float2*)(f + (size_t)b * FEAT))[lane];
    const float2 ft2 = ((const float2*)(f + (size_t)BATCH * FEAT + (size_t)b * FEAT))[lane];

    int k0 = tile * KPB;
    int k1 = k0 + KPB; if (k1 > KP1) k1 = KP1;

    float s1 = 0.f, s2 = 0.f;
    for (int k = k0 + wave; k < k1; k += 4) {
        int fi = (k == 0) ? idx[b] : cidx[(size_t)b * 8192 + (k - 1)];
        const float2* r1 = (const float2*)(mem_v1 + (size_t)fi * FEAT);
        const float2* r2 = (const float2*)(mem_v2 + (size_t)fi * FEAT);
        float2 a1 = r1[lane];
        float2 a2 = r2[lane];
        float dt = a1.x * ft2.x + a1.y * ft2.y;   // v1 rows pair with f_t -> out_v2
        float ds = a2.x * fs2.x + a2.y * fs2.y;   // v2 rows pair with f_s -> out_v1
        dt = wave_reduce(dt);
        ds = wave_reduce(ds);
        float ov2 = expf(dt * INVT);
        float ov1 = expf(ds * INVT);
        if (lane == 0) {
            out_v2[(size_t)b * KP1 + k] = ov2;
            out_v1[(size_t)b * KP1 + k] = ov1;
        }
        s1 += ov1; s2 += ov2;
    }
    __shared__ float ls1[4], ls2[4];
    if (lane == 0) { ls1[wave] = s1; ls2[wave] = s2; }
    __syncthreads();
    if (threadIdx.x == 0) {
        int pbid = b * KT + tile;
        partials[2 * pbid + 0] = ls1[0] + ls1[1] + ls1[2] + ls1[3];
        partials[2 * pbid + 1] = ls2[0] + ls2[1] + ls2[2] + ls2[3];
    }
}

// ---------------- kernel 3: reduce partials -> Z ----------------
__global__ void zreduce_kernel(const float* __restrict__ partials, float* __restrict__ Z) {
    __shared__ float sh1[256], sh2[256];
    int t = threadIdx.x;
    float a1 = 0.f, a2 = 0.f;
    for (int i = t; i < NBLK_GATHER; i += 256) { a1 += partials[2*i]; a2 += partials[2*i+1]; }
    sh1[t] = a1; sh2[t] = a2; __syncthreads();
    for (int s = 128; s > 0; s >>= 1) {
        if (t < s) { sh1[t] += sh1[t+s]; sh2[t] += sh2[t+s]; }
        __syncthreads();
    }
    if (t == 0) {
        const float scale = 1000000.0f / (float)TOT_OUT;  // mean * N_DATA
        Z[0] = sh1[0] * scale;   // Z_v1 (for out_v1 -> out_s)
        Z[1] = sh2[0] * scale;   // Z_v2 (for out_v2 -> out_t)
    }
}

// ---------------- kernel 4: per-element loss terms ----------------
__global__ void loss_kernel(const float* __restrict__ out_v1, const float* __restrict__ out_v2,
                            const float* __restrict__ Z, double* __restrict__ lpart) {
    const float cc = 8192.0f / 1000000.0f;   // m * Pn
    const float ce = cc + 1e-7f;             // c + EPS
    float z0 = Z[0], z1 = Z[1];
    int gid = blockIdx.x * blockDim.x + threadIdx.x;
    int stride = gridDim.x * blockDim.x;
    double acc = 0.0;
    for (int e = gid; e < 2 * TOT_OUT; e += stride) {
        int arr = (e >= TOT_OUT);
        int r   = arr ? (e - TOT_OUT) : e;
        int k   = r % KP1;
        float o = (arr ? out_v2[r] : out_v1[r]) / (arr ? z1 : z0);
        float denom = o + ce;
        float term = (k == 0) ? logf(o / denom) : logf(cc / denom);
        acc += (double)term;
    }
    __shared__ double sh[256];
    sh[threadIdx.x] = acc; __syncthreads();
    for (int s = 128; s > 0; s >>= 1) {
        if (threadIdx.x < s) sh[threadIdx.x] += sh[threadIdx.x + s];
        __syncthreads();
    }
    if (threadIdx.x == 0) lpart[blockIdx.x] = sh[0];
}

// ---------------- kernel 5: final reduce -> loss ----------------
__global__ void final_kernel(const double* __restrict__ lpart, float* __restrict__ out) {
    __shared__ double sh[256];
    double acc = 0.0;
    for (int i = threadIdx.x; i < NBLK_LOSS; i += 256) acc += lpart[i];
    sh[threadIdx.x] = acc; __syncthreads();
    for (int s = 128; s > 0; s >>= 1) {
        if (threadIdx.x < s) sh[threadIdx.x] += sh[threadIdx.x + s];
        __syncthreads();
    }
    if (threadIdx.x == 0) out[0] = (float)(-sh[0] / (double)BATCH);
}

extern "C" void kernel_launch(void* const* d_in, const int* in_sizes, int n_in,
                              void* d_out, int out_size, void* d_ws, size_t ws_size,
                              hipStream_t stream) {
    const float* x_s   = (const float*)d_in[0];
    const float* x_t   = (const float*)d_in[1];
    const float* W_s   = (const float*)d_in[2];
    const float* b_s   = (const float*)d_in[3];
    const float* W_t   = (const float*)d_in[4];
    const float* b_t   = (const float*)d_in[5];
    const float* mem_v1 = (const float*)d_in[6];
    const float* mem_v2 = (const float*)d_in[7];
    const int*   idx   = (const int*)d_in[8];
    const int*   cidx  = (const int*)d_in[9];
    float* out = (float*)d_out;

    // workspace layout (floats)
    float* ws = (float*)d_ws;
    float* f      = ws;                         // 2*32*128 = 8192
    float* out_v1 = f + 2 * BATCH * FEAT;       // 262176
    float* out_v2 = out_v1 + TOT_OUT;           // 262176
    float* parts  = out_v2 + TOT_OUT;           // 2*2048 = 4096
    float* Z      = parts + 2 * NBLK_GATHER;    // 2
    // align doubles to 8 bytes
    size_t off_f = (size_t)(Z + 2 - ws);
    off_f = (off_f + 1) & ~(size_t)1;
    double* lpart = (double*)(ws + off_f);      // 512 doubles

    embed_kernel<<<64, 256, 0, stream>>>(x_s, x_t, W_s, b_s, W_t, b_t, f);
    gather_kernel<<<dim3(KT, BATCH), 256, 0, stream>>>(mem_v1, mem_v2, f, idx, cidx,
                                                        out_v1, out_v2, parts);
    zreduce_kernel<<<1, 256, 0, stream>>>(parts, Z);
    loss_kernel<<<NBLK_LOSS, 256, 0, stream>>>(out_v1, out_v2, Z, lpart);
    final_kernel<<<1, 256, 0, stream>>>(lpart, out);
}